// Round 14
// baseline (35.658 us; speedup 1.0000x reference)
//
#include <hip/hip_runtime.h>
#include <math.h>

// YOLOv3 detection-head decode — line-aligned tiling, single fused pass.
// prediction: [B=32, 255, 52, 52] f32 ; anchors: [3,2] f32
// out: [B, 52*52*3, 85] f32 ; flat out elem = (b*2704 + s)*255 + c,
// s = gj*52+gi, c = a*85+attr.
//
// Unit = 16 consecutive s: input = one aligned 64B line per c-row (255
// exclusive lines); output = 4080 contiguous floats = 255 aligned lines.
//   Load : 255 lines -> LDS in output order (16,320B, 8 blocks/CU).
//   Store: 4x { ds_read_b128 -> decode -> dwordx4 } per thread; decode is
//          sigmoid everywhere + PREDICATED special path for the 12/255
//          x/y/w/h columns (attr<4), folded inline (R13's deferred fixup
//          RMW'd evicted lines: WRITE 104 MB; this writes each line once).
// XCD swizzle: each XCD owns a contiguous group range.

#define GG 52
#define NROWS 255
#define PLANE 2704             // 52*52, flat s
#define NGRP 5408              // 32 * 169 groups of 16 s
#define L2E 1.442695040889f

typedef float f32x4 __attribute__((ext_vector_type(4)));

__device__ __forceinline__ float fast_sigmoid(float x) {
    return __builtin_amdgcn_rcpf(1.0f + __builtin_amdgcn_exp2f(-L2E * x));
}

__device__ __forceinline__ void scatter(float* __restrict__ tile, int idx,
                                        f32x4 v) {
    // element (c = idx>>2, s_l = 4*(idx&3)+k) -> e = s_l*255 + c
    const int e = (idx & 3) * 4 * NROWS + (idx >> 2);
    tile[e            ] = v.x;
    tile[e +     NROWS] = v.y;
    tile[e + 2 * NROWS] = v.z;
    tile[e + 3 * NROWS] = v.w;
}

__global__ __launch_bounds__(256, 8)
void detect_decode_kernel(const float* __restrict__ in,
                          const float* __restrict__ anchors,
                          float* __restrict__ out) {
    __shared__ float tile[16 * NROWS];   // 16,320 B, output order

    // XCD swizzle: XCD x owns contiguous grp range
    const int B   = blockIdx.x;
    const int g   = (B & 7) * (NGRP / 8) + (B >> 3);   // 0..5407
    const int b   = g / 169;
    const int s0  = (g - b * 169) * 16;
    const int t   = threadIdx.x;

    const float* __restrict__ src = in + (size_t)b * NROWS * PLANE + s0;

    // ---- load: 255 exclusive aligned lines -> output-order LDS ----
    const int i0 = t;
    const int i1 = t + 256;
    const int i2 = t + 512;
    const int i3 = (t + 768 < 1020) ? t + 768 : 1019;   // clamp, no guard

    const f32x4 v0 = *reinterpret_cast<const f32x4*>(src + (size_t)(i0 >> 2) * PLANE + (i0 & 3) * 4);
    const f32x4 v1 = *reinterpret_cast<const f32x4*>(src + (size_t)(i1 >> 2) * PLANE + (i1 & 3) * 4);
    const f32x4 v2 = *reinterpret_cast<const f32x4*>(src + (size_t)(i2 >> 2) * PLANE + (i2 & 3) * 4);
    const f32x4 v3 = *reinterpret_cast<const f32x4*>(src + (size_t)(i3 >> 2) * PLANE + (i3 & 3) * 4);

    scatter(tile, i0, v0);
    scatter(tile, i1, v1);
    scatter(tile, i2, v2);
    scatter(tile, i3, v3);   // clamped lanes rewrite identical values: benign

    __syncthreads();

    // anchors in named regs (no runtime-indexed array -> no scratch)
    const float a0x = anchors[0], a0y = anchors[1];
    const float a1x = anchors[2], a1y = anchors[3];
    const float a2x = anchors[4], a2y = anchors[5];

    float* __restrict__ dst = out + ((size_t)b * PLANE + s0) * NROWS;

    #pragma unroll
    for (int it = 0; it < 4; ++it) {
        const int i = (it == 0) ? i0 : (it == 1) ? i1 : (it == 2) ? i2 : i3;
        const f32x4 u = *reinterpret_cast<const f32x4*>(&tile[4 * i]);

        const int e0  = 4 * i;
        const int sl0 = e0 / NROWS;            // magic div, 0..15
        const int c00 = e0 - sl0 * NROWS;

        f32x4 o;
        #pragma unroll
        for (int k = 0; k < 4; ++k) {
            const int wrap = (c00 + k >= NROWS) ? 1 : 0;
            const int c    = c00 + k - (wrap ? NROWS : 0);
            const int s_l  = sl0 + wrap;
            const int a    = (c >= 170) ? 2 : (c >= 85 ? 1 : 0);
            const int attr = c - a * 85;

            const float x  = (k == 0) ? u.x : (k == 1) ? u.y
                           : (k == 2) ? u.z : u.w;
            const float sg = fast_sigmoid(x);

            float r = sg;
            if (attr < 4) {                    // 12/255 columns: predicated
                const int s  = s0 + s_l;
                const int gj = s / GG;         // magic div
                const int gi = s - gj * GG;
                const float off = (attr == 0) ? (float)gi : (float)gj;
                const float anc =
                    (attr == 2) ? ((a == 0) ? a0x : (a == 1) ? a1x : a2x)
                                : ((a == 0) ? a0y : (a == 1) ? a1y : a2y);
                r = (attr < 2) ? (sg + off) * 8.0f
                               : __builtin_amdgcn_exp2f(L2E * x) * anc;
            }

            if (k == 0) o.x = r; else if (k == 1) o.y = r;
            else if (k == 2) o.z = r; else o.w = r;
        }

        *reinterpret_cast<f32x4*>(dst + 4 * i) = o;
    }
}

extern "C" void kernel_launch(void* const* d_in, const int* in_sizes, int n_in,
                              void* d_out, int out_size, void* d_ws, size_t ws_size,
                              hipStream_t stream) {
    const float* pred    = (const float*)d_in[0];
    const float* anchors = (const float*)d_in[1];
    float* out = (float*)d_out;

    detect_decode_kernel<<<NGRP, 256, 0, stream>>>(pred, anchors, out);
}

// Round 15
// 31.533 us; speedup vs baseline: 1.1308x; 1.1308x over previous
//
#include <hip/hip_runtime.h>
#include <math.h>

// YOLOv3 detection-head decode — decode-in-load-phase, pure-copy store phase.
// prediction: [B=32, 255, 52, 52] f32 ; anchors: [3,2] f32
// out: [B, 52*52*3, 85] f32 ; flat out elem = (b*2704 + s)*255 + c,
// s = gj*52+gi, c = a*85+attr.
//
// Unit = 16 consecutive s: input = one aligned 64B line per c-row (255
// exclusive lines); output = 4080 contiguous floats = 255 aligned lines.
//
// R15 insight: in the LOAD phase c = idx>>2 is per-thread CONSTANT, so the
// attr decode is per-thread (not per-element), and the special columns
// {0-3, 85-88, 170-173} hit only 3 of 16 wave-iterations (c-windows
// [0,16),[80,96),[160,176)) -> s_cbranch_execz skips the slow block in the
// other 13. LDS receives FINAL values; the store phase is a pure
// ds_read_b128 -> dwordx4 copy with ZERO arithmetic. One barrier, no RMW
// fixup (R13's +18 MB), no per-element decode (R14's 49% VALU).
// gi/gj via block-uniform gj0/rem0 + adds (no per-element magic div).

#define GG 52
#define NROWS 255
#define PLANE 2704             // 52*52, flat s
#define NGRP 5408              // 32 * 169 groups of 16 s
#define L2E 1.442695040889f

typedef float f32x4 __attribute__((ext_vector_type(4)));

__device__ __forceinline__ float fast_sigmoid(float x) {
    return __builtin_amdgcn_rcpf(1.0f + __builtin_amdgcn_exp2f(-L2E * x));
}

__global__ __launch_bounds__(256, 8)
void detect_decode_kernel(const float* __restrict__ in,
                          const float* __restrict__ anchors,
                          float* __restrict__ out) {
    __shared__ float tile[16 * NROWS];   // 16,320 B, FINAL values, output order

    // XCD swizzle: XCD x owns contiguous grp range
    const int B    = blockIdx.x;
    const int g    = (B & 7) * (NGRP / 8) + (B >> 3);   // 0..5407
    const int b    = g / 169;
    const int s0   = (g - b * 169) * 16;
    const int gj0  = s0 / GG;            // block-uniform
    const int rem0 = s0 - gj0 * GG;      // 0..51
    const int t    = threadIdx.x;

    const float* __restrict__ src = in + (size_t)b * NROWS * PLANE + s0;

    const float a0x = anchors[0], a0y = anchors[1];
    const float a1x = anchors[2], a1y = anchors[3];
    const float a2x = anchors[4], a2y = anchors[5];

    // ---- load + decode: c per-thread constant; specials in 3/16 wave-its ----
    #pragma unroll
    for (int it = 0; it < 4; ++it) {
        int idx = t + it * 256;
        if (idx > 1019) idx = 1019;              // clamp (c=254, not special)
        const int c = idx >> 2;
        const int q = idx & 3;

        const f32x4 v = *reinterpret_cast<const f32x4*>(
            src + (size_t)c * PLANE + 4 * q);

        f32x4 r;
        r.x = fast_sigmoid(v.x);
        r.y = fast_sigmoid(v.y);
        r.z = fast_sigmoid(v.z);
        r.w = fast_sigmoid(v.w);

        const bool sp0 = c < 4;
        const bool sp1 = (unsigned)(c - 85)  < 4u;
        const bool sp2 = (unsigned)(c - 170) < 4u;
        if (__builtin_expect(sp0 | sp1 | sp2, 0)) {
            const int attr = sp0 ? c : (sp1 ? c - 85 : c - 170);
            const float ancx = sp0 ? a0x : (sp1 ? a1x : a2x);
            const float ancy = sp0 ? a0y : (sp1 ? a1y : a2y);
            const float anc  = (attr == 2) ? ancx : ancy;
            #pragma unroll
            for (int k = 0; k < 4; ++k) {
                const int rem = rem0 + 4 * q + k;     // < 67: one wrap max
                const int wv  = (rem >= GG) ? 1 : 0;
                const int gi  = rem - (wv ? GG : 0);
                const int gj  = gj0 + wv;
                const float x  = v[k];
                const float sg = r[k];
                float rr;
                if (attr == 0)      rr = (sg + (float)gi) * 8.0f;
                else if (attr == 1) rr = (sg + (float)gj) * 8.0f;
                else                rr = __builtin_amdgcn_exp2f(L2E * x) * anc;
                r[k] = rr;
            }
        }

        // scatter: element (c, s_l = 4q+k) -> e = s_l*255 + c
        const int e = q * 4 * NROWS + c;
        tile[e            ] = r.x;
        tile[e +     NROWS] = r.y;
        tile[e + 2 * NROWS] = r.z;
        tile[e + 3 * NROWS] = r.w;
    }

    __syncthreads();

    // ---- store: pure copy, zero arithmetic ----
    float* __restrict__ dst = out + ((size_t)b * PLANE + s0) * NROWS;

    const int i0 = t;
    const int i1 = t + 256;
    const int i2 = t + 512;
    const int i3 = (t + 768 < 1020) ? t + 768 : 1019;

    const f32x4 u0 = *reinterpret_cast<const f32x4*>(&tile[4 * i0]);
    const f32x4 u1 = *reinterpret_cast<const f32x4*>(&tile[4 * i1]);
    const f32x4 u2 = *reinterpret_cast<const f32x4*>(&tile[4 * i2]);
    const f32x4 u3 = *reinterpret_cast<const f32x4*>(&tile[4 * i3]);

    *reinterpret_cast<f32x4*>(dst + 4 * i0) = u0;
    *reinterpret_cast<f32x4*>(dst + 4 * i1) = u1;
    *reinterpret_cast<f32x4*>(dst + 4 * i2) = u2;
    *reinterpret_cast<f32x4*>(dst + 4 * i3) = u3;
}

extern "C" void kernel_launch(void* const* d_in, const int* in_sizes, int n_in,
                              void* d_out, int out_size, void* d_ws, size_t ws_size,
                              hipStream_t stream) {
    const float* pred    = (const float*)d_in[0];
    const float* anchors = (const float*)d_in[1];
    float* out = (float*)d_out;

    detect_decode_kernel<<<NGRP, 256, 0, stream>>>(pred, anchors, out);
}